// Round 2
// baseline (312.960 us; speedup 1.0000x reference)
//
#include <hip/hip_runtime.h>
#include <hip/hip_bf16.h>

typedef __hip_bfloat16 bf16;
typedef unsigned short u16;
typedef __attribute__((ext_vector_type(8))) short bf16x8;     // MFMA A/B frag: 8 bf16 = 4 VGPRs
typedef __attribute__((ext_vector_type(4))) float f32x4;      // MFMA C/D frag
typedef __attribute__((ext_vector_type(8))) unsigned short u16x8;

#define KD 1024
#define HD 1024
#define BSZ 8192
#define BM 128
#define BN 64
#define BK 32

// ws layout (bytes): wt [0, 12582912) | bxf [12582912,+12288) | bhf [12595200,+12288) | flag [12607488,+4)
#define WS_BXF 12582912
#define WS_BHF 12595200
#define WS_FLAG 12607488

// ---------------------------------------------------------------------------
// Kernel 0: dtype probe. Even 16-bit halfwords of x: bf16 data -> real bf16
// values (exponent in N(0,1) band); f32 data -> mantissa halves (uniform bits).
// flag=1 means bf16, flag=0 means f32.
// ---------------------------------------------------------------------------
__global__ void probe_dtype(const u16* __restrict__ xs, int* __restrict__ flag) {
    int lane = threadIdx.x;   // <<<1,64>>>
    int cnt = 0;
    #pragma unroll
    for (int j = 0; j < 8; j++) {
        u16 u = xs[(lane * 8 + j) * 2];
        int e = (u >> 7) & 0xFF;
        cnt += (e >= 0x60 && e <= 0x85) ? 1 : 0;
    }
    for (int off = 32; off > 0; off >>= 1) cnt += __shfl_down(cnt, off);
    if (lane == 0) *flag = (cnt >= 307) ? 1 : 0;   // 60% of 512 samples
}

// ---------------------------------------------------------------------------
// Kernel 1: biases -> f32 in ws (uniform epilogue path).
// ---------------------------------------------------------------------------
__global__ __launch_bounds__(256) void prep_bias(
    const void* __restrict__ bx, const void* __restrict__ bh,
    float* __restrict__ bxf, float* __restrict__ bhf, const int* __restrict__ flag) {
    const int isbf = *flag;
    int id = blockIdx.x * 256 + threadIdx.x;       // <<<24,256>>> covers 6144
    const void* src = (id < 3072) ? bx : bh;
    float* dst = (id < 3072) ? bxf : bhf;
    int k = (id < 3072) ? id : id - 3072;
    dst[k] = isbf ? __bfloat162float(((const bf16*)src)[k]) : ((const float*)src)[k];
}

// ---------------------------------------------------------------------------
// Kernel 2: transpose weights [g][k][n] -> wt[g][n][k] in bf16 (rounding f32
// sources). K-contiguous rows let the GEMM use ds_read_b128 B-fragments.
// ---------------------------------------------------------------------------
__global__ __launch_bounds__(256) void transpose_w(
    const void* __restrict__ wx, const void* __restrict__ wh,
    u16* __restrict__ wt, const int* __restrict__ flag)
{
    __shared__ u16 tile[64][65];   // +1 pad breaks bank collisions
    const int isbf = *flag;
    const int g = blockIdx.z;
    const void* src = (g < 3) ? wx : wh;
    const size_t goff = (size_t)((g < 3) ? g : g - 3) * KD * HD;
    u16* dst = wt + (size_t)g * KD * HD;
    const int r0 = blockIdx.y * 64;   // k rows in src
    const int c0 = blockIdx.x * 64;   // n cols in src
    const int t = threadIdx.x;

    #pragma unroll
    for (int r = 0; r < 2; r++) {
        int idx = r * 256 + t;
        int row = idx >> 3, cc = idx & 7;
        size_t si = goff + (size_t)(r0 + row) * HD + c0 + cc * 8;
        u16x8 v;
        if (isbf) {
            v = *(const u16x8*)((const u16*)src + si);
        } else {
            const float* p = (const float*)src + si;
            #pragma unroll
            for (int e = 0; e < 8; e++)
                v[e] = __builtin_bit_cast(u16, __float2bfloat16(p[e]));
        }
        #pragma unroll
        for (int e = 0; e < 8; e++) tile[row][cc * 8 + e] = v[e];
    }
    __syncthreads();
    #pragma unroll
    for (int r = 0; r < 2; r++) {
        int idx = r * 256 + t;
        int nrow = idx >> 3, kc = idx & 7;
        u16x8 v;
        #pragma unroll
        for (int e = 0; e < 8; e++) v[e] = tile[kc * 8 + e][nrow];
        *(u16x8*)(dst + (size_t)(c0 + nrow) * KD + r0 + kc * 8) = v;
    }
}

// ---------------------------------------------------------------------------
// Kernel 3: fused GRU cell. Per 128x64 tile, 4 accumulators:
//   acc0 = x@Wxr + h@Whr   acc1 = x@Wxz + h@Whz   acc2 = x@Wxn   acc3 = h@Whn
// epilogue: r=sig(acc0+b), z=sig(acc1+b), n=tanh(acc2+bxn + r*(acc3+bhn)),
// out = (1-z)*n + z*h. Manual LDS staging (no global_load_lds this round).
// ---------------------------------------------------------------------------
__global__ __launch_bounds__(256, 2) void gru_fused(
    const void* __restrict__ xg, const void* __restrict__ hg,
    const u16* __restrict__ wt, const float* __restrict__ bxf,
    const float* __restrict__ bhf, const int* __restrict__ flag,
    void* __restrict__ outg)
{
    // smem (u16 elems): sX [0,4096) sH [4096,8192) sW [8192 + g*2048 + n*32 + k)
    __shared__ u16 smem[20480];   // 40 KiB
    const int isbf = *flag;
    const int t    = threadIdx.x;
    const int lane = t & 63;
    const int w    = t >> 6;
    const int wm   = w >> 1, wn = w & 1;
    const int quad = lane >> 4;
    const int c16  = lane & 15;
    const int m0   = blockIdx.y * BM;
    const int n0   = blockIdx.x * BN;
    const int row4 = t >> 2;        // staging: thread t covers 16B chunk t
    const int e8   = (t & 3) * 8;

    f32x4 acc[4][4][2];
    #pragma unroll
    for (int a = 0; a < 4; a++)
        #pragma unroll
        for (int i = 0; i < 4; i++)
            #pragma unroll
            for (int j = 0; j < 2; j++)
                acc[a][i][j] = (f32x4){0.f, 0.f, 0.f, 0.f};

    for (int k0 = 0; k0 < KD; k0 += BK) {
        // ---- stage A tiles (x, hid): 128 rows x 32 k, bf16 in LDS ----
        #pragma unroll
        for (int s = 0; s < 2; s++) {
            size_t gidx = (size_t)(m0 + s * 64 + row4) * KD + k0 + e8;
            u16x8 vx, vh;
            if (isbf) {
                vx = *(const u16x8*)((const u16*)xg + gidx);
                vh = *(const u16x8*)((const u16*)hg + gidx);
            } else {
                const float* px = (const float*)xg + gidx;
                const float* ph = (const float*)hg + gidx;
                #pragma unroll
                for (int e = 0; e < 8; e++) {
                    vx[e] = __builtin_bit_cast(u16, __float2bfloat16(px[e]));
                    vh[e] = __builtin_bit_cast(u16, __float2bfloat16(ph[e]));
                }
            }
            *(u16x8*)&smem[s * 2048 + t * 8] = vx;
            *(u16x8*)&smem[4096 + s * 2048 + t * 8] = vh;
        }
        // ---- stage 6 weight tiles (64 n-rows x 32 k, already bf16) ----
        #pragma unroll
        for (int g = 0; g < 6; g++) {
            u16x8 vw = *(const u16x8*)(wt + (size_t)g * KD * HD + (size_t)(n0 + row4) * KD + k0 + e8);
            *(u16x8*)&smem[8192 + g * 2048 + t * 8] = vw;
        }
        __syncthreads();

        bf16x8 ax[4], ah[4];
        #pragma unroll
        for (int i = 0; i < 4; i++) {
            int ml = wm * 64 + i * 16 + c16;
            ax[i] = *(const bf16x8*)&smem[ml * BK + quad * 8];
            ah[i] = *(const bf16x8*)&smem[4096 + ml * BK + quad * 8];
        }
        #pragma unroll
        for (int p = 0; p < 3; p++) {           // gates r, z, n
            bf16x8 bwx[2], bwh[2];
            #pragma unroll
            for (int j = 0; j < 2; j++) {
                int nl = wn * 32 + j * 16 + c16;
                bwx[j] = *(const bf16x8*)&smem[8192 + p * 2048       + nl * BK + quad * 8];
                bwh[j] = *(const bf16x8*)&smem[8192 + (p + 3) * 2048 + nl * BK + quad * 8];
            }
            #pragma unroll
            for (int i = 0; i < 4; i++)
                #pragma unroll
                for (int j = 0; j < 2; j++) {
                    if (p < 2) {
                        acc[p][i][j] = __builtin_amdgcn_mfma_f32_16x16x32_bf16(ax[i], bwx[j], acc[p][i][j], 0, 0, 0);
                        acc[p][i][j] = __builtin_amdgcn_mfma_f32_16x16x32_bf16(ah[i], bwh[j], acc[p][i][j], 0, 0, 0);
                    } else {
                        acc[2][i][j] = __builtin_amdgcn_mfma_f32_16x16x32_bf16(ax[i], bwx[j], acc[2][i][j], 0, 0, 0);
                        acc[3][i][j] = __builtin_amdgcn_mfma_f32_16x16x32_bf16(ah[i], bwh[j], acc[3][i][j], 0, 0, 0);
                    }
                }
        }
        __syncthreads();
    }

    // ---- epilogue: C/D layout col=lane&15, row=quad*4+reg ----
    float bR[2], bZ[2], bXN[2], bHN[2];
    #pragma unroll
    for (int j = 0; j < 2; j++) {
        int col = n0 + wn * 32 + j * 16 + c16;
        bR[j]  = bxf[col]          + bhf[col];
        bZ[j]  = bxf[HD + col]     + bhf[HD + col];
        bXN[j] = bxf[2 * HD + col];
        bHN[j] = bhf[2 * HD + col];
    }
    #pragma unroll
    for (int i = 0; i < 4; i++)
        #pragma unroll
        for (int j = 0; j < 2; j++) {
            int col = n0 + wn * 32 + j * 16 + c16;
            #pragma unroll
            for (int r = 0; r < 4; r++) {
                int row = m0 + wm * 64 + i * 16 + quad * 4 + r;
                size_t idx = (size_t)row * HD + col;
                float vr = acc[0][i][j][r] + bR[j];
                vr = 1.f / (1.f + __expf(-vr));
                float vz = acc[1][i][j][r] + bZ[j];
                vz = 1.f / (1.f + __expf(-vz));
                float vn = (acc[2][i][j][r] + bXN[j]) + vr * (acc[3][i][j][r] + bHN[j]);
                float e2 = __expf(2.f * vn);
                vn = 1.f - 2.f / (e2 + 1.f);
                float h = isbf ? __bfloat162float(((const bf16*)hg)[idx])
                               : ((const float*)hg)[idx];
                float o = (1.f - vz) * vn + vz * h;
                if (isbf) ((bf16*)outg)[idx] = __float2bfloat16(o);
                else      ((float*)outg)[idx] = o;
            }
        }
}

extern "C" void kernel_launch(void* const* d_in, const int* in_sizes, int n_in,
                              void* d_out, int out_size, void* d_ws, size_t ws_size,
                              hipStream_t stream) {
    const void* x   = d_in[0];
    const void* hid = d_in[1];
    const void* wx  = d_in[2];
    const void* wh  = d_in[3];
    const void* bx  = d_in[4];
    const void* bh  = d_in[5];

    char* ws = (char*)d_ws;
    u16*   wt   = (u16*)ws;
    float* bxf  = (float*)(ws + WS_BXF);
    float* bhf  = (float*)(ws + WS_BHF);
    int*   flag = (int*)(ws + WS_FLAG);

    probe_dtype<<<1, 64, 0, stream>>>((const u16*)x, flag);
    prep_bias<<<24, 256, 0, stream>>>(bx, bh, bxf, bhf, flag);
    dim3 tgrid(HD / 64, KD / 64, 6);
    transpose_w<<<tgrid, 256, 0, stream>>>(wx, wh, wt, flag);
    dim3 ggrid(HD / BN, BSZ / BM);   // 16 x 64 = 1024 blocks
    gru_fused<<<ggrid, 256, 0, stream>>>(x, hid, wt, bxf, bhf, flag, d_out);
}

// Round 3
// 254.456 us; speedup vs baseline: 1.2299x; 1.2299x over previous
//
#include <hip/hip_runtime.h>
#include <hip/hip_bf16.h>

typedef __hip_bfloat16 bf16;
typedef unsigned short u16;
typedef __attribute__((ext_vector_type(8))) short bf16x8;     // MFMA A/B frag: 8 bf16 = 4 VGPRs
typedef __attribute__((ext_vector_type(4))) float f32x4;      // MFMA C/D frag
typedef __attribute__((ext_vector_type(8))) unsigned short u16x8;

#define KD 1024
#define HD 1024
#define BSZ 8192
#define BM 128
#define BN 64
#define BK 32

// ws layout (bytes): wt [0, 12582912) | xb [12582912, +16777216) | hb [29360128, +16777216)
#define WS_XB 12582912
#define WS_HB 29360128
#define WS_NEED 46137344ULL

__device__ __forceinline__ u16 f2b(float f) {
    return __builtin_bit_cast(u16, __float2bfloat16(f));
}

// ---- async global->LDS, 16B per lane, wave-uniform LDS base + lane*16 ----
__device__ __forceinline__ void gload16(const void* g, u16* smem, int lds_byte_off) {
    __builtin_amdgcn_global_load_lds(
        (const __attribute__((address_space(1))) void*)g,
        (__attribute__((address_space(3))) void*)((char*)smem + lds_byte_off),
        16, 0, 0);
}

// ---------------------------------------------------------------------------
// Kernel A: one-shot f32 -> bf16 conversion of x and hid (removes 16x
// redundant in-loop conversion: 512 MB -> 33.5 MB of converted data).
// ---------------------------------------------------------------------------
__global__ __launch_bounds__(256) void convert_xh(
    const float* __restrict__ x, const float* __restrict__ h,
    u16* __restrict__ xb, u16* __restrict__ hb)
{
    size_t off = ((size_t)blockIdx.x * 256 + threadIdx.x) * 8;   // <<<4096,256>>> covers 8M elems
    float4 a0 = *(const float4*)(x + off);
    float4 a1 = *(const float4*)(x + off + 4);
    float4 b0 = *(const float4*)(h + off);
    float4 b1 = *(const float4*)(h + off + 4);
    u16x8 vx, vh;
    vx[0]=f2b(a0.x); vx[1]=f2b(a0.y); vx[2]=f2b(a0.z); vx[3]=f2b(a0.w);
    vx[4]=f2b(a1.x); vx[5]=f2b(a1.y); vx[6]=f2b(a1.z); vx[7]=f2b(a1.w);
    vh[0]=f2b(b0.x); vh[1]=f2b(b0.y); vh[2]=f2b(b0.z); vh[3]=f2b(b0.w);
    vh[4]=f2b(b1.x); vh[5]=f2b(b1.y); vh[6]=f2b(b1.z); vh[7]=f2b(b1.w);
    *(u16x8*)(xb + off) = vx;
    *(u16x8*)(hb + off) = vh;
}

// ---------------------------------------------------------------------------
// Kernel B: transpose+cast weights [g][k][n] f32 -> wt[g][n][k] bf16.
// K-contiguous rows enable ds_read_b128 B-fragments in the GEMM.
// ---------------------------------------------------------------------------
__global__ __launch_bounds__(256) void transpose_w(
    const float* __restrict__ wx, const float* __restrict__ wh, u16* __restrict__ wt)
{
    __shared__ u16 tile[64][65];   // +1 pad breaks bank collisions
    const int g = blockIdx.z;
    const float* src = (g < 3) ? (wx + (size_t)g * KD * HD) : (wh + (size_t)(g - 3) * KD * HD);
    u16* dst = wt + (size_t)g * KD * HD;
    const int r0 = blockIdx.y * 64;   // k rows in src
    const int c0 = blockIdx.x * 64;   // n cols in src
    const int t = threadIdx.x;

    #pragma unroll
    for (int r = 0; r < 2; r++) {
        int idx = r * 256 + t;
        int row = idx >> 3, cc = idx & 7;
        const float* p = src + (size_t)(r0 + row) * HD + c0 + cc * 8;
        #pragma unroll
        for (int e = 0; e < 8; e++) tile[row][cc * 8 + e] = f2b(p[e]);
    }
    __syncthreads();
    #pragma unroll
    for (int r = 0; r < 2; r++) {
        int idx = r * 256 + t;
        int nrow = idx >> 3, kc = idx & 7;
        u16x8 v;
        #pragma unroll
        for (int e = 0; e < 8; e++) v[e] = tile[kc * 8 + e][nrow];
        *(u16x8*)(dst + (size_t)(c0 + nrow) * KD + r0 + kc * 8) = v;
    }
}

// ---------------------------------------------------------------------------
// Epilogue shared by both GEMM variants. C/D layout: col=lane&15, row=quad*4+r.
// ---------------------------------------------------------------------------
__device__ __forceinline__ void gru_epilogue(
    f32x4 (&acc)[4][4][2], const float* __restrict__ bxf, const float* __restrict__ bhf,
    const float* __restrict__ hidf, float* __restrict__ outf,
    int m0, int n0, int wm, int wn, int quad, int c16)
{
    float bR[2], bZ[2], bXN[2], bHN[2];
    #pragma unroll
    for (int j = 0; j < 2; j++) {
        int col = n0 + wn * 32 + j * 16 + c16;
        bR[j]  = bxf[col]          + bhf[col];
        bZ[j]  = bxf[HD + col]     + bhf[HD + col];
        bXN[j] = bxf[2 * HD + col];
        bHN[j] = bhf[2 * HD + col];
    }
    #pragma unroll
    for (int i = 0; i < 4; i++)
        #pragma unroll
        for (int j = 0; j < 2; j++) {
            int col = n0 + wn * 32 + j * 16 + c16;
            #pragma unroll
            for (int r = 0; r < 4; r++) {
                int row = m0 + wm * 64 + i * 16 + quad * 4 + r;
                size_t idx = (size_t)row * HD + col;
                float vr = acc[0][i][j][r] + bR[j];
                vr = 1.f / (1.f + __expf(-vr));
                float vz = acc[1][i][j][r] + bZ[j];
                vz = 1.f / (1.f + __expf(-vz));
                float vn = (acc[2][i][j][r] + bXN[j]) + vr * (acc[3][i][j][r] + bHN[j]);
                float e2 = __expf(2.f * vn);
                vn = 1.f - 2.f / (e2 + 1.f);
                float o = (1.f - vz) * vn + vz * hidf[idx];
                outf[idx] = o;
            }
        }
}

// ---------------------------------------------------------------------------
// Kernel C (fast): pure global_load_lds staging — no ds_writes, no VALU
// conversion in the hot loop. 4 acc sets: r(shared), z(shared), nx, nh.
// smem bytes: x [0,8192) h [8192,16384) w [16384 + g*4096)
// ---------------------------------------------------------------------------
__global__ __launch_bounds__(256, 2) void gru_fused_fast(
    const u16* __restrict__ xb, const u16* __restrict__ hb,
    const u16* __restrict__ wt,
    const float* __restrict__ bxf, const float* __restrict__ bhf,
    const float* __restrict__ hidf, float* __restrict__ outf)
{
    __shared__ u16 smem[20480];   // 40 KiB
    const int t    = threadIdx.x;
    const int lane = t & 63;
    const int w    = t >> 6;
    const int wm   = w >> 1, wn = w & 1;
    const int quad = lane >> 4;
    const int c16  = lane & 15;
    // XCD swizzle: linear % 8 presumed XCD; give each XCD 2 n-blocks so its
    // 1.57 MB weight slice stays L2-resident.
    const int lin  = blockIdx.x;
    const int nblk = (lin & 7) * 2 + ((lin >> 3) & 1);
    const int mblk = lin >> 4;
    const int m0   = mblk * BM;
    const int n0   = nblk * BN;

    const int row4 = t >> 2;
    const int e8   = (t & 3) * 8;
    const u16* gx0 = xb + (size_t)(m0 + row4) * KD + e8;
    const u16* gx1 = gx0 + (size_t)64 * KD;
    const u16* gh0 = hb + (size_t)(m0 + row4) * KD + e8;
    const u16* gh1 = gh0 + (size_t)64 * KD;
    const u16* gw0 = wt + (size_t)(n0 + row4) * KD + e8;
    const int ldsl = w * 1024;   // wave-uniform LDS byte base (lane adds *16)

    f32x4 acc[4][4][2];
    #pragma unroll
    for (int a = 0; a < 4; a++)
        #pragma unroll
        for (int i = 0; i < 4; i++)
            #pragma unroll
            for (int j = 0; j < 2; j++)
                acc[a][i][j] = (f32x4){0.f, 0.f, 0.f, 0.f};

    for (int k0 = 0; k0 < KD; k0 += BK) {
        gload16(gx0, smem, ldsl);
        gload16(gx1, smem, 4096 + ldsl);
        gload16(gh0, smem, 8192 + ldsl);
        gload16(gh1, smem, 12288 + ldsl);
        #pragma unroll
        for (int g = 0; g < 6; g++)
            gload16(gw0 + (size_t)g * KD * HD, smem, 16384 + g * 4096 + ldsl);
        __syncthreads();
        gx0 += BK; gx1 += BK; gh0 += BK; gh1 += BK; gw0 += BK;

        bf16x8 ax[4], ah[4];
        #pragma unroll
        for (int i = 0; i < 4; i++) {
            int ml = wm * 64 + i * 16 + c16;
            ax[i] = *(const bf16x8*)&smem[ml * BK + quad * 8];
            ah[i] = *(const bf16x8*)&smem[4096 + ml * BK + quad * 8];
        }
        #pragma unroll
        for (int p = 0; p < 3; p++) {
            bf16x8 bwx[2], bwh[2];
            #pragma unroll
            for (int j = 0; j < 2; j++) {
                int nl = wn * 32 + j * 16 + c16;
                bwx[j] = *(const bf16x8*)&smem[8192 + p * 2048       + nl * BK + quad * 8];
                bwh[j] = *(const bf16x8*)&smem[8192 + (p + 3) * 2048 + nl * BK + quad * 8];
            }
            #pragma unroll
            for (int i = 0; i < 4; i++)
                #pragma unroll
                for (int j = 0; j < 2; j++) {
                    if (p < 2) {
                        acc[p][i][j] = __builtin_amdgcn_mfma_f32_16x16x32_bf16(ax[i], bwx[j], acc[p][i][j], 0, 0, 0);
                        acc[p][i][j] = __builtin_amdgcn_mfma_f32_16x16x32_bf16(ah[i], bwh[j], acc[p][i][j], 0, 0, 0);
                    } else {
                        acc[2][i][j] = __builtin_amdgcn_mfma_f32_16x16x32_bf16(ax[i], bwx[j], acc[2][i][j], 0, 0, 0);
                        acc[3][i][j] = __builtin_amdgcn_mfma_f32_16x16x32_bf16(ah[i], bwh[j], acc[3][i][j], 0, 0, 0);
                    }
                }
        }
        __syncthreads();
    }

    gru_epilogue(acc, bxf, bhf, hidf, outf, m0, n0, wm, wn, quad, c16);
}

// ---------------------------------------------------------------------------
// Kernel C' (fallback if ws too small for xb/hb): in-loop f32->bf16 convert
// for x/h; weights still via global_load_lds. Same LDS layout.
// ---------------------------------------------------------------------------
__global__ __launch_bounds__(256, 2) void gru_fused_slow(
    const float* __restrict__ xf, const float* __restrict__ hf,
    const u16* __restrict__ wt,
    const float* __restrict__ bxf, const float* __restrict__ bhf,
    float* __restrict__ outf)
{
    __shared__ u16 smem[20480];
    const int t    = threadIdx.x;
    const int lane = t & 63;
    const int w    = t >> 6;
    const int wm   = w >> 1, wn = w & 1;
    const int quad = lane >> 4;
    const int c16  = lane & 15;
    const int lin  = blockIdx.x;
    const int nblk = (lin & 7) * 2 + ((lin >> 3) & 1);
    const int mblk = lin >> 4;
    const int m0   = mblk * BM;
    const int n0   = nblk * BN;
    const int row4 = t >> 2;
    const int e8   = (t & 3) * 8;
    const u16* gw0 = wt + (size_t)(n0 + row4) * KD + e8;
    const int ldsl = w * 1024;

    f32x4 acc[4][4][2];
    #pragma unroll
    for (int a = 0; a < 4; a++)
        #pragma unroll
        for (int i = 0; i < 4; i++)
            #pragma unroll
            for (int j = 0; j < 2; j++)
                acc[a][i][j] = (f32x4){0.f, 0.f, 0.f, 0.f};

    for (int k0 = 0; k0 < KD; k0 += BK) {
        #pragma unroll
        for (int g = 0; g < 6; g++)
            gload16(gw0 + (size_t)g * KD * HD, smem, 16384 + g * 4096 + ldsl);
        gw0 += BK;
        #pragma unroll
        for (int s = 0; s < 2; s++) {
            size_t gidx = (size_t)(m0 + s * 64 + row4) * KD + k0 + e8;
            const float* px = xf + gidx;
            const float* ph = hf + gidx;
            u16x8 vx, vh;
            #pragma unroll
            for (int e = 0; e < 8; e++) { vx[e] = f2b(px[e]); vh[e] = f2b(ph[e]); }
            *(u16x8*)&smem[s * 2048 + t * 8] = vx;
            *(u16x8*)&smem[4096 + s * 2048 + t * 8] = vh;
        }
        __syncthreads();

        bf16x8 ax[4], ah[4];
        #pragma unroll
        for (int i = 0; i < 4; i++) {
            int ml = wm * 64 + i * 16 + c16;
            ax[i] = *(const bf16x8*)&smem[ml * BK + quad * 8];
            ah[i] = *(const bf16x8*)&smem[4096 + ml * BK + quad * 8];
        }
        #pragma unroll
        for (int p = 0; p < 3; p++) {
            bf16x8 bwx[2], bwh[2];
            #pragma unroll
            for (int j = 0; j < 2; j++) {
                int nl = wn * 32 + j * 16 + c16;
                bwx[j] = *(const bf16x8*)&smem[8192 + p * 2048       + nl * BK + quad * 8];
                bwh[j] = *(const bf16x8*)&smem[8192 + (p + 3) * 2048 + nl * BK + quad * 8];
            }
            #pragma unroll
            for (int i = 0; i < 4; i++)
                #pragma unroll
                for (int j = 0; j < 2; j++) {
                    if (p < 2) {
                        acc[p][i][j] = __builtin_amdgcn_mfma_f32_16x16x32_bf16(ax[i], bwx[j], acc[p][i][j], 0, 0, 0);
                        acc[p][i][j] = __builtin_amdgcn_mfma_f32_16x16x32_bf16(ah[i], bwh[j], acc[p][i][j], 0, 0, 0);
                    } else {
                        acc[2][i][j] = __builtin_amdgcn_mfma_f32_16x16x32_bf16(ax[i], bwx[j], acc[2][i][j], 0, 0, 0);
                        acc[3][i][j] = __builtin_amdgcn_mfma_f32_16x16x32_bf16(ah[i], bwh[j], acc[3][i][j], 0, 0, 0);
                    }
                }
        }
        __syncthreads();
    }

    gru_epilogue(acc, bxf, bhf, hf, outf, m0, n0, wm, wn, quad, c16);
}

extern "C" void kernel_launch(void* const* d_in, const int* in_sizes, int n_in,
                              void* d_out, int out_size, void* d_ws, size_t ws_size,
                              hipStream_t stream) {
    const float* x   = (const float*)d_in[0];
    const float* hid = (const float*)d_in[1];
    const float* wx  = (const float*)d_in[2];
    const float* wh  = (const float*)d_in[3];
    const float* bx  = (const float*)d_in[4];
    const float* bh  = (const float*)d_in[5];
    float* out = (float*)d_out;

    char* ws = (char*)d_ws;
    u16* wt = (u16*)ws;
    u16* xb = (u16*)(ws + WS_XB);
    u16* hb = (u16*)(ws + WS_HB);

    dim3 tgrid(HD / 64, KD / 64, 6);
    transpose_w<<<tgrid, 256, 0, stream>>>(wx, wh, wt);

    if (ws_size >= WS_NEED) {
        convert_xh<<<4096, 256, 0, stream>>>(x, hid, xb, hb);
        gru_fused_fast<<<1024, 256, 0, stream>>>(xb, hb, wt, bx, bh, hid, out);
    } else {
        gru_fused_slow<<<1024, 256, 0, stream>>>(x, hid, wt, bx, bh, out);
    }
}